// Round 3
// baseline (692.415 us; speedup 1.0000x reference)
//
#include <hip/hip_runtime.h>
#include <math.h>

// ConvCaps EM routing, fp32 I/O. n=392 positions, one 1024-thread block each.
// KK=288 votes, C=32 out-caps, 16 pose elems. v=P@W recomputed per pass
// (W 576KB fp32, L2-resident). Fused EM: pre-normalization folded into
// pass-2 tail via f_k = a/(a+eps) (softmax over c sums to 1).

#define NTH 1024
#define KK 288
#define KT 9          // 288 / 32
#define CC 32
#define PS 16
#define EPSF 1e-8f
#define LAMF 1e-3f

__device__ __forceinline__ float4 ld4(const float* p){ return *(const float4*)p; }
__device__ __forceinline__ float rcpf(float x){ return __builtin_amdgcn_rcpf(x); }

extern "C" __global__ void __launch_bounds__(NTH, 8)
convcaps_em_kernel(const float* __restrict__ x, const float* __restrict__ wgt,
                   const float* __restrict__ beta_a, const float* __restrict__ beta_u,
                   float* __restrict__ out)
{
  __shared__ float sP[KK*PS];      // poses, group-swizzled (18432 B)
  __shared__ float sA[KK];         // f = a/(a+eps) after staging (1152 B)
  __shared__ float sR[KK*33];      // normalized rr, stride 33 (38016 B)
  __shared__ float sMu[CC*17];     // (2176 B)
  __shared__ float sNI2[CC*17];    // -0.5/sigma^2 (2176 B)
  __shared__ float sLs[CC], sLnA[CC], sAo[CC], sRsum[CC], sInvR[CC]; // 640 B
  __shared__ float sRp[16*CC];     // per-wave r_sum partials (2048 B)
  // total 64640 B

  const int tid = threadIdx.x;
  const int n   = blockIdx.x;
  const int b   = n / 49;
  const int r49 = n - b*49;
  const int ohi = r49 / 7;
  const int owi = r49 - ohi*7;

  const float* xw = x + ((size_t)b*16 + (size_t)(ohi*2))*16*544 + (size_t)(owi*2)*544;

  const int c1  = tid >> 5;   // pass-1: k-reduce over ks1 in 32-lane half
  const int ks1 = tid & 31;
  const int c2  = tid & 31;   // pass-2: c-softmax over lanes
  const int ks2 = tid >> 5;
  const int wv  = tid >> 6;   // wave id 0..15

  // ---- stage poses (swizzled) ----
  for (int idx = tid; idx < KK*PS/4; idx += NTH) {   // 1152 float4s
    const int sp  = idx >> 7;
    const int ch4 = idx & 127;
    const int kh = sp/3, kw = sp - kh*3;
    const float4 v = ld4(&xw[kh*(16*544) + kw*544 + ch4*4]);
    const int k = sp*32 + (ch4 >> 2);
    const int g = ch4 & 3;
    *(float4*)&sP[(k<<4) + ((g ^ ((k>>1)&3))<<2)] = v;
  }
  // ---- stage activations ----
  if (tid < KK/4) {
    const int sp  = tid >> 3;
    const int bc4 = tid & 7;
    const int kh = sp/3, kw = sp - kh*3;
    const float4 v = ld4(&xw[kh*(16*544) + kw*544 + 512 + bc4*4]);
    *(float4*)&sA[sp*32 + bc4*4] = v;
  }
  __syncthreads();
  // f = a/(a+eps) in place
  if (tid < KK) { const float a = sA[tid]; sA[tid] = a * rcpf(a + EPSF); }
  __syncthreads();
  // iteration-0 rr = f/32 (uniform over c)
  for (int j = 0; j < 9; ++j) {
    const int idx = tid + j*NTH;
    sR[(idx>>5)*33 + (idx&31)] = sA[idx>>5] * (1.0f/32.0f);
  }
  __syncthreads();

  // r_sum reduction helper: thread holds partial over its (ks2, kt) k's.
  auto reduce_rsum = [&](float part){
    part += __shfl_xor(part, 32);
    if ((tid & 32) == 0) sRp[wv*32 + c2] = part;
    __syncthreads();
    if (tid < CC) {
      float s = 0.f;
#pragma unroll
      for (int j = 0; j < 16; ++j) s += sRp[j*32 + tid];
      sRsum[tid] = s;
      sInvR[tid] = rcpf(s + EPSF);
    }
    __syncthreads();
  };

  // iteration-0 r_sum (read sR back)
  {
    float part = 0.f;
#pragma unroll
    for (int kt = 0; kt < KT; ++kt) part += sR[(kt*32 + ks2)*33 + c2];
    reduce_rsum(part);
  }

  for (int it = 0; it < 3; ++it) {
    // ---- pass 1: fused moments (s0, s1, s2) over k ----
    float s0 = 0.f, s1[PS], s2[PS];
#pragma unroll
    for (int p = 0; p < PS; ++p) { s1[p] = 0.f; s2[p] = 0.f; }
    const float invr = sInvR[c1];
    for (int kt = 0; kt < KT; ++kt) {
      const int k = kt*32 + ks1;
      const float4* wg = (const float4*)(wgt + (((size_t)(k*32 + c1)) << 4));
      const float4 w0 = wg[0], w1 = wg[1], w2 = wg[2], w3 = wg[3];
      const int sw = (k>>1)&3;
      const float* pb = &sP[k<<4];
      const float4 P0 = ld4(pb + ((0^sw)<<2));
      const float4 P1 = ld4(pb + ((1^sw)<<2));
      const float4 P2 = ld4(pb + ((2^sw)<<2));
      const float4 P3 = ld4(pb + ((3^sw)<<2));
      const float co = sR[k*33 + c1] * invr;
      s0 += co;
      const float4 Pi[4] = {P0, P1, P2, P3};
#pragma unroll
      for (int i = 0; i < 4; ++i) {
        float v0 = Pi[i].x*w0.x; v0 = fmaf(Pi[i].y, w1.x, v0); v0 = fmaf(Pi[i].z, w2.x, v0); v0 = fmaf(Pi[i].w, w3.x, v0);
        float v1 = Pi[i].x*w0.y; v1 = fmaf(Pi[i].y, w1.y, v1); v1 = fmaf(Pi[i].z, w2.y, v1); v1 = fmaf(Pi[i].w, w3.y, v1);
        float v2 = Pi[i].x*w0.z; v2 = fmaf(Pi[i].y, w1.z, v2); v2 = fmaf(Pi[i].z, w2.z, v2); v2 = fmaf(Pi[i].w, w3.z, v2);
        float v3 = Pi[i].x*w0.w; v3 = fmaf(Pi[i].y, w1.w, v3); v3 = fmaf(Pi[i].z, w2.w, v3); v3 = fmaf(Pi[i].w, w3.w, v3);
        const float c0f = co*v0, c1f = co*v1, c2f = co*v2, c3f = co*v3;
        s1[i*4+0] += c0f; s2[i*4+0] = fmaf(c0f, v0, s2[i*4+0]);
        s1[i*4+1] += c1f; s2[i*4+1] = fmaf(c1f, v1, s2[i*4+1]);
        s1[i*4+2] += c2f; s2[i*4+2] = fmaf(c2f, v2, s2[i*4+2]);
        s1[i*4+3] += c3f; s2[i*4+3] = fmaf(c3f, v3, s2[i*4+3]);
      }
    }
#pragma unroll
    for (int m = 1; m <= 16; m <<= 1) {
      s0 += __shfl_xor(s0, m);
#pragma unroll
      for (int p = 0; p < PS; ++p) {
        s1[p] += __shfl_xor(s1[p], m);
        s2[p] += __shfl_xor(s2[p], m);
      }
    }
    if (ks1 == 0) {
      const float rsum = sRsum[c1];
      float lsum = 0.f;
#pragma unroll
      for (int p = 0; p < PS; ++p) {
        const float mu = s1[p];
        const float var = fmaxf(s2[p] - mu*mu*(2.0f - s0), 0.f) + EPSF;
        const float ls = 0.5f * __logf(var);
        lsum += ls;
        sMu[c1*17 + p]  = mu;
        sNI2[c1*17 + p] = -0.5f * rcpf(var);
      }
      const float cost = (16.f*beta_u[c1] + lsum) * rsum;
      const float ao = rcpf(1.f + __expf(-(LAMF*(beta_a[c1] - cost))));
      sAo[c1]  = ao;
      sLnA[c1] = __logf(ao);
      sLs[c1]  = lsum;
    }
    __syncthreads();

    // ---- pass 2: ln_p -> softmax over c -> rr (normalized) + r_sum ----
    if (it < 2) {
      float mu[PS], ni2[PS];
#pragma unroll
      for (int p = 0; p < PS; ++p) { mu[p] = sMu[c2*17+p]; ni2[p] = sNI2[c2*17+p]; }
      const float lc = sLnA[c2] - sLs[c2] - 16.f*0.91893853320467274178f;
      float part = 0.f;
      for (int kt = 0; kt < KT; ++kt) {
        const int k = kt*32 + ks2;
        const float4* wg = (const float4*)(wgt + (((size_t)(k*32 + c2)) << 4));
        const float4 w0 = wg[0], w1 = wg[1], w2 = wg[2], w3 = wg[3];
        const int sw = (k>>1)&3;
        const float* pb = &sP[k<<4];
        const float4 P0 = ld4(pb + ((0^sw)<<2));
        const float4 P1 = ld4(pb + ((1^sw)<<2));
        const float4 P2 = ld4(pb + ((2^sw)<<2));
        const float4 P3 = ld4(pb + ((3^sw)<<2));
        const float4 Pi[4] = {P0, P1, P2, P3};
        float acc = 0.f;
#pragma unroll
        for (int i = 0; i < 4; ++i) {
          float v0 = Pi[i].x*w0.x; v0 = fmaf(Pi[i].y, w1.x, v0); v0 = fmaf(Pi[i].z, w2.x, v0); v0 = fmaf(Pi[i].w, w3.x, v0);
          float v1 = Pi[i].x*w0.y; v1 = fmaf(Pi[i].y, w1.y, v1); v1 = fmaf(Pi[i].z, w2.y, v1); v1 = fmaf(Pi[i].w, w3.y, v1);
          float v2 = Pi[i].x*w0.z; v2 = fmaf(Pi[i].y, w1.z, v2); v2 = fmaf(Pi[i].z, w2.z, v2); v2 = fmaf(Pi[i].w, w3.z, v2);
          float v3 = Pi[i].x*w0.w; v3 = fmaf(Pi[i].y, w1.w, v3); v3 = fmaf(Pi[i].z, w2.w, v3); v3 = fmaf(Pi[i].w, w3.w, v3);
          const float d0 = v0 - mu[i*4+0], d1 = v1 - mu[i*4+1];
          const float d2 = v2 - mu[i*4+2], d3 = v3 - mu[i*4+3];
          acc = fmaf(d0*d0, ni2[i*4+0], acc);
          acc = fmaf(d1*d1, ni2[i*4+1], acc);
          acc = fmaf(d2*d2, ni2[i*4+2], acc);
          acc = fmaf(d3*d3, ni2[i*4+3], acc);
        }
        const float lnap = acc + lc;
        float m = lnap;
        m = fmaxf(m, __shfl_xor(m, 1));  m = fmaxf(m, __shfl_xor(m, 2));
        m = fmaxf(m, __shfl_xor(m, 4));  m = fmaxf(m, __shfl_xor(m, 8));
        m = fmaxf(m, __shfl_xor(m, 16));
        const float e = __expf(lnap - m);
        float s = e;
        s += __shfl_xor(s, 1);  s += __shfl_xor(s, 2);  s += __shfl_xor(s, 4);
        s += __shfl_xor(s, 8);  s += __shfl_xor(s, 16);
        const float rr = e * rcpf(s) * sA[k];   // r * a/(a+eps): pre-normalized
        part += rr;
        sR[k*33 + c2] = rr;
      }
      __syncthreads();        // sR writes complete before anyone re-reads
      reduce_rsum(part);
    }
  }
  __syncthreads();

  // ---- epilogue ----
  if (tid < 512)      out[(size_t)n*544 + tid] = sMu[(tid>>4)*17 + (tid&15)];
  else if (tid < 544) out[(size_t)n*544 + tid] = sAo[tid - 512];
}

extern "C" void kernel_launch(void* const* d_in, const int* in_sizes, int n_in,
                              void* d_out, int out_size, void* d_ws, size_t ws_size,
                              hipStream_t stream) {
  (void)in_sizes; (void)n_in; (void)d_ws; (void)ws_size; (void)out_size;
  const float* x  = (const float*)d_in[0];
  const float* w  = (const float*)d_in[1];
  const float* ba = (const float*)d_in[2];
  const float* bu = (const float*)d_in[3];
  float* out = (float*)d_out;
  convcaps_em_kernel<<<dim3(392), dim3(NTH), 0, stream>>>(x, w, ba, bu, out);
}

// Round 5
// 205.182 us; speedup vs baseline: 3.3746x; 3.3746x over previous
//
#include <hip/hip_runtime.h>
#include <math.h>

// ConvCaps EM routing, fp32 I/O. n=392 positions, one 512-thread block each
// (R2-proven skeleton: passed full tripwire battery; the 1024-thread fused
// variants R3/R4 carry a latent timing-dependent defect -> abandoned).
// KK=288 votes, C=32 out-caps, 16 pose elems. v=P@W recomputed per pass
// (W 576KB fp32, L2-resident).
// R5 deltas vs R2: sP xor-swizzle (conflict-free at 16-lane layout),
// sR stride 34 (2-way max everywhere), pre-A pass fused away via
// f=a/(a+eps) (softmax over c sums to 1), fast intrinsics.

#define NTH 512
#define KK 288
#define KT 18         // 288 / 16
#define CC 32
#define PS 16
#define SRS 34        // sR stride: bank=(2k+c)%32 -> <=2-way (free)
#define EPSF 1e-8f
#define LAMF 1e-3f

__device__ __forceinline__ float4 ld4(const float* p){ return *(const float4*)p; }
__device__ __forceinline__ float rcpf(float x){ return __builtin_amdgcn_rcpf(x); }

extern "C" __global__ void __launch_bounds__(NTH)
convcaps_em_kernel(const float* __restrict__ x, const float* __restrict__ wgt,
                   const float* __restrict__ beta_a, const float* __restrict__ beta_u,
                   float* __restrict__ out)
{
  __shared__ float sP[KK*PS];      // poses, xor-swizzled groups (18432 B)
  __shared__ float sA[KK];         // f = a/(a+eps) after staging (1152 B)
  __shared__ float sR[KK*SRS];     // rr (pre-normalized), stride 34 (39168 B)
  __shared__ float sMu[CC*17];     // (2176 B)
  __shared__ float sNI2[CC*17];    // -0.5/sigma^2 (2176 B)
  __shared__ float sLs[CC], sLnA[CC], sAo[CC], sRsum[CC], sInvR[CC]; // 640 B
  // total 63744 B

  const int tid = threadIdx.x;
  const int n   = blockIdx.x;
  const int b   = n / 49;
  const int r49 = n - b*49;
  const int ohi = r49 / 7;
  const int owi = r49 - ohi*7;

  const float* xw = x + ((size_t)b*16 + (size_t)(ohi*2))*16*544 + (size_t)(owi*2)*544;

  const int c1  = tid >> 4;   // pass-1 / r_sum layout: k-reduce over 16 lanes
  const int ks1 = tid & 15;
  const int c2  = tid & 31;   // pass-2 layout: c-softmax over 32 lanes
  const int ks2 = tid >> 5;   // 0..15

  // ---- stage poses (swizzled groups: logical g stored at g^((k>>1)&3)) ----
  for (int idx = tid; idx < KK*PS/4; idx += NTH) {   // 1152 float4s
    const int sp  = idx >> 7;          // 0..8
    const int ch4 = idx & 127;
    const int kh = sp/3, kw = sp - kh*3;
    const float4 v = ld4(&xw[kh*(16*544) + kw*544 + ch4*4]);
    const int k = sp*32 + (ch4 >> 2);
    const int g = ch4 & 3;
    *(float4*)&sP[(k<<4) + ((g ^ ((k>>1)&3))<<2)] = v;
  }
  // ---- stage activations ----
  if (tid < KK/4) {
    const int sp  = tid >> 3;
    const int bc4 = tid & 7;
    const int kh = sp/3, kw = sp - kh*3;
    const float4 v = ld4(&xw[kh*(16*544) + kw*544 + 512 + bc4*4]);
    *(float4*)&sA[sp*32 + bc4*4] = v;
  }
  __syncthreads();
  // f = a/(a+eps) in place
  if (tid < KK) { const float a = sA[tid]; sA[tid] = a * rcpf(a + EPSF); }
  __syncthreads();
  // iteration-0 rr = f/32 (uniform over c)
  for (int j = 0; j < KK*CC/NTH; ++j) {
    const int idx = tid + j*NTH;
    sR[(idx>>5)*SRS + (idx&31)] = sA[idx>>5] * (1.0f/32.0f);
  }
  __syncthreads();

  // ---- r_sum phase (R2-proven pattern): read-reduce sR at 16-lane layout ----
  // (executed before the loop and after each pass-2)
  {
    float s = 0.f;
#pragma unroll
    for (int kt = 0; kt < KT; ++kt) s += sR[(kt*16 + ks1)*SRS + c1];
    s += __shfl_xor(s, 1);  s += __shfl_xor(s, 2);
    s += __shfl_xor(s, 4);  s += __shfl_xor(s, 8);
    if (ks1 == 0) { sRsum[c1] = s; sInvR[c1] = rcpf(s + EPSF); }
  }
  __syncthreads();

  for (int it = 0; it < 3; ++it) {
    // ---- pass 1: fused moments (s0, s1, s2) over k ----
    float s0 = 0.f, s1[PS], s2[PS];
#pragma unroll
    for (int p = 0; p < PS; ++p) { s1[p] = 0.f; s2[p] = 0.f; }
    const float invr = sInvR[c1];
    for (int kt = 0; kt < KT; ++kt) {
      const int k = kt*16 + ks1;
      const float4* wg = (const float4*)(wgt + (((size_t)(k*32 + c1)) << 4));
      const float4 w0 = wg[0], w1 = wg[1], w2 = wg[2], w3 = wg[3];
      const int sw = (k>>1)&3;
      const float* pb = &sP[k<<4];
      const float4 Pi0 = ld4(pb + ((0^sw)<<2));
      const float4 Pi1 = ld4(pb + ((1^sw)<<2));
      const float4 Pi2 = ld4(pb + ((2^sw)<<2));
      const float4 Pi3 = ld4(pb + ((3^sw)<<2));
      const float co = sR[k*SRS + c1] * invr;
      s0 += co;
      const float4 Pi[4] = {Pi0, Pi1, Pi2, Pi3};
#pragma unroll
      for (int i = 0; i < 4; ++i) {
        float v0 = Pi[i].x*w0.x; v0 = fmaf(Pi[i].y, w1.x, v0); v0 = fmaf(Pi[i].z, w2.x, v0); v0 = fmaf(Pi[i].w, w3.x, v0);
        float v1 = Pi[i].x*w0.y; v1 = fmaf(Pi[i].y, w1.y, v1); v1 = fmaf(Pi[i].z, w2.y, v1); v1 = fmaf(Pi[i].w, w3.y, v1);
        float v2 = Pi[i].x*w0.z; v2 = fmaf(Pi[i].y, w1.z, v2); v2 = fmaf(Pi[i].z, w2.z, v2); v2 = fmaf(Pi[i].w, w3.z, v2);
        float v3 = Pi[i].x*w0.w; v3 = fmaf(Pi[i].y, w1.w, v3); v3 = fmaf(Pi[i].z, w2.w, v3); v3 = fmaf(Pi[i].w, w3.w, v3);
        const float c0f = co*v0, c1f = co*v1, c2f = co*v2, c3f = co*v3;
        s1[i*4+0] += c0f; s2[i*4+0] = fmaf(c0f, v0, s2[i*4+0]);
        s1[i*4+1] += c1f; s2[i*4+1] = fmaf(c1f, v1, s2[i*4+1]);
        s1[i*4+2] += c2f; s2[i*4+2] = fmaf(c2f, v2, s2[i*4+2]);
        s1[i*4+3] += c3f; s2[i*4+3] = fmaf(c3f, v3, s2[i*4+3]);
      }
    }
#pragma unroll
    for (int m = 1; m <= 8; m <<= 1) {
      s0 += __shfl_xor(s0, m);
#pragma unroll
      for (int p = 0; p < PS; ++p) {
        s1[p] += __shfl_xor(s1[p], m);
        s2[p] += __shfl_xor(s2[p], m);
      }
    }
    if (ks1 == 0) {
      const float rsum = sRsum[c1];
      float lsum = 0.f;
#pragma unroll
      for (int p = 0; p < PS; ++p) {
        const float mu = s1[p];
        const float var = fmaxf(s2[p] - mu*mu*(2.0f - s0), 0.f) + EPSF;
        const float ls = 0.5f * __logf(var);
        lsum += ls;
        sMu[c1*17 + p]  = mu;
        sNI2[c1*17 + p] = -0.5f * rcpf(var);
      }
      const float cost = (16.f*beta_u[c1] + lsum) * rsum;
      const float ao = rcpf(1.f + __expf(-(LAMF*(beta_a[c1] - cost))));
      sAo[c1]  = ao;
      sLnA[c1] = __logf(ao);
      sLs[c1]  = lsum;
    }
    __syncthreads();

    // ---- pass 2: ln_p -> softmax over c -> rr = r * f (pre-normalized) ----
    if (it < 2) {
      float mu[PS], ni2[PS];
#pragma unroll
      for (int p = 0; p < PS; ++p) { mu[p] = sMu[c2*17+p]; ni2[p] = sNI2[c2*17+p]; }
      const float lc = sLnA[c2] - sLs[c2] - 16.f*0.91893853320467274178f;
      for (int kt = 0; kt < KT; ++kt) {
        const int k = kt*16 + ks2;
        const float4* wg = (const float4*)(wgt + (((size_t)(k*32 + c2)) << 4));
        const float4 w0 = wg[0], w1 = wg[1], w2 = wg[2], w3 = wg[3];
        const int sw = (k>>1)&3;
        const float* pb = &sP[k<<4];
        const float4 Pi0 = ld4(pb + ((0^sw)<<2));
        const float4 Pi1 = ld4(pb + ((1^sw)<<2));
        const float4 Pi2 = ld4(pb + ((2^sw)<<2));
        const float4 Pi3 = ld4(pb + ((3^sw)<<2));
        const float4 Pi[4] = {Pi0, Pi1, Pi2, Pi3};
        float acc = 0.f;
#pragma unroll
        for (int i = 0; i < 4; ++i) {
          float v0 = Pi[i].x*w0.x; v0 = fmaf(Pi[i].y, w1.x, v0); v0 = fmaf(Pi[i].z, w2.x, v0); v0 = fmaf(Pi[i].w, w3.x, v0);
          float v1 = Pi[i].x*w0.y; v1 = fmaf(Pi[i].y, w1.y, v1); v1 = fmaf(Pi[i].z, w2.y, v1); v1 = fmaf(Pi[i].w, w3.y, v1);
          float v2 = Pi[i].x*w0.z; v2 = fmaf(Pi[i].y, w1.z, v2); v2 = fmaf(Pi[i].z, w2.z, v2); v2 = fmaf(Pi[i].w, w3.z, v2);
          float v3 = Pi[i].x*w0.w; v3 = fmaf(Pi[i].y, w1.w, v3); v3 = fmaf(Pi[i].z, w2.w, v3); v3 = fmaf(Pi[i].w, w3.w, v3);
          const float d0 = v0 - mu[i*4+0], d1 = v1 - mu[i*4+1];
          const float d2 = v2 - mu[i*4+2], d3 = v3 - mu[i*4+3];
          acc = fmaf(d0*d0, ni2[i*4+0], acc);
          acc = fmaf(d1*d1, ni2[i*4+1], acc);
          acc = fmaf(d2*d2, ni2[i*4+2], acc);
          acc = fmaf(d3*d3, ni2[i*4+3], acc);
        }
        const float lnap = acc + lc;
        float m = lnap;
        m = fmaxf(m, __shfl_xor(m, 1));  m = fmaxf(m, __shfl_xor(m, 2));
        m = fmaxf(m, __shfl_xor(m, 4));  m = fmaxf(m, __shfl_xor(m, 8));
        m = fmaxf(m, __shfl_xor(m, 16));
        const float e = __expf(lnap - m);
        float s = e;
        s += __shfl_xor(s, 1);  s += __shfl_xor(s, 2);  s += __shfl_xor(s, 4);
        s += __shfl_xor(s, 8);  s += __shfl_xor(s, 16);
        sR[k*SRS + c2] = e * rcpf(s) * sA[k];   // r * a/(a+eps)
      }
      __syncthreads();

      // ---- r_sum phase (same proven pattern) ----
      {
        float s = 0.f;
#pragma unroll
        for (int kt = 0; kt < KT; ++kt) s += sR[(kt*16 + ks1)*SRS + c1];
        s += __shfl_xor(s, 1);  s += __shfl_xor(s, 2);
        s += __shfl_xor(s, 4);  s += __shfl_xor(s, 8);
        if (ks1 == 0) { sRsum[c1] = s; sInvR[c1] = rcpf(s + EPSF); }
      }
      __syncthreads();
    }
  }
  __syncthreads();

  // ---- epilogue ----
  out[(size_t)n*544 + tid] = sMu[(tid>>4)*17 + (tid&15)];
  if (tid < CC) out[(size_t)n*544 + 512 + tid] = sAo[tid];
}

extern "C" void kernel_launch(void* const* d_in, const int* in_sizes, int n_in,
                              void* d_out, int out_size, void* d_ws, size_t ws_size,
                              hipStream_t stream) {
  (void)in_sizes; (void)n_in; (void)d_ws; (void)ws_size; (void)out_size;
  const float* x  = (const float*)d_in[0];
  const float* w  = (const float*)d_in[1];
  const float* ba = (const float*)d_in[2];
  const float* bu = (const float*)d_in[3];
  float* out = (float*)d_out;
  convcaps_em_kernel<<<dim3(392), dim3(NTH), 0, stream>>>(x, w, ba, bu, out);
}

// Round 6
// 156.686 us; speedup vs baseline: 4.4191x; 1.3095x over previous
//
#include <hip/hip_runtime.h>
#include <math.h>

// ConvCaps EM routing, fp32 I/O. n=392 positions, one 512-thread block each.
// R6: merged-pass structure — each EM iteration computes v = P@W exactly once
// (3 sweeps total vs R5's 5). Per (k,c): ln_p from previous mu/sigma ->
// in-wave softmax over c -> rr -> accumulate UNNORMALIZED moments t0,t1,t2;
// stats phase normalizes (mu = t1/(t0+eps), r_sum = t0). sR buffer and both
// r_sum phases are gone. k-reduction: shfl_xor(32) ks-pair fold + 8 wave
// partials in LDS (stride 33 = conflict-free) + (c,p)-per-thread stats.
// 512 threads / default bounds: the R5-proven config (1024-thr variants had
// a timing-dependent defect; R3's (1024,8) spilled to 32 VGPR).

#define NTH 512
#define KK 288
#define KT 18         // 288 / 16 k-groups
#define CC 32
#define PS 16
#define EPSF 1e-8f
#define LAMF 1e-3f
#define HL2PI 0.91893853320467274178f   // 0.5*ln(2*pi)

__device__ __forceinline__ float4 ld4(const float* p){ return *(const float4*)p; }
__device__ __forceinline__ float rcpf(float x){ return __builtin_amdgcn_rcpf(x); }

extern "C" __global__ void __launch_bounds__(NTH)
convcaps_em_kernel(const float* __restrict__ x, const float* __restrict__ wgt,
                   const float* __restrict__ beta_a, const float* __restrict__ beta_u,
                   float* __restrict__ out)
{
  __shared__ float sP[KK*PS];        // poses, xor-swizzled groups (18432 B)
  __shared__ float sA[KK];           // f = a/(a+eps) (1152 B)
  __shared__ float sPart[8*CC*33];   // wave partials t0|t1[16]|t2[16] (33792 B)
  __shared__ float sMu[CC*17];       // (2176 B)
  __shared__ float sNI2[CC*17];      // -0.5/sigma^2 (2176 B)
  __shared__ float sLs[CC], sLnA[CC], sAo[CC];   // 384 B
  // total ~58.1 KB

  const int tid = threadIdx.x;
  const int n   = blockIdx.x;
  const int b   = n / 49;
  const int r49 = n - b*49;
  const int ohi = r49 / 7;
  const int owi = r49 - ohi*7;

  const float* xw = x + ((size_t)b*16 + (size_t)(ohi*2))*16*544 + (size_t)(owi*2)*544;

  const int c  = tid & 31;    // sweep layout: c in-wave (softmax over c)
  const int ks = tid >> 5;    // k-group 0..15 (k = kt*16 + ks)
  const int w  = tid >> 6;    // wave 0..7
  const int cc = tid >> 4;    // stats layout: one thread per (cc, pp)
  const int pp = tid & 15;

  // ---- stage poses (xor-swizzled groups, R5-validated) ----
  for (int idx = tid; idx < KK*PS/4; idx += NTH) {   // 1152 float4s
    const int sp  = idx >> 7;
    const int ch4 = idx & 127;
    const int kh = sp/3, kw = sp - kh*3;
    const float4 v = ld4(&xw[kh*(16*544) + kw*544 + ch4*4]);
    const int k = sp*32 + (ch4 >> 2);
    const int g = ch4 & 3;
    *(float4*)&sP[(k<<4) + ((g ^ ((k>>1)&3))<<2)] = v;
  }
  // ---- stage activations ----
  if (tid < KK/4) {
    const int sp  = tid >> 3;
    const int bc4 = tid & 7;
    const int kh = sp/3, kw = sp - kh*3;
    const float4 v = ld4(&xw[kh*(16*544) + kw*544 + 512 + bc4*4]);
    *(float4*)&sA[sp*32 + bc4*4] = v;
  }
  __syncthreads();
  if (tid < KK) { const float a = sA[tid]; sA[tid] = a * rcpf(a + EPSF); }
  __syncthreads();

  float t0, t1[PS], t2[PS];

  // ---- stats phase: fold ks-pairs, reduce 8 wave partials, write mu/sigma/a ----
  auto stats = [&](){
    t0 += __shfl_xor(t0, 32);
#pragma unroll
    for (int p = 0; p < PS; ++p) {
      t1[p] += __shfl_xor(t1[p], 32);
      t2[p] += __shfl_xor(t2[p], 32);
    }
    if ((tid & 32) == 0) {             // one lane-half per wave writes
      float* pr = &sPart[(w*CC + c)*33];   // stride 33: (c+j)%32 conflict-free
      pr[0] = t0;
#pragma unroll
      for (int p = 0; p < PS; ++p) { pr[1+p] = t1[p]; pr[17+p] = t2[p]; }
    }
    __syncthreads();
    {
      float T0 = 0.f, T1 = 0.f, T2 = 0.f;
#pragma unroll
      for (int j = 0; j < 8; ++j) {
        const float* pr = &sPart[(j*CC + cc)*33];
        T0 += pr[0]; T1 += pr[1+pp]; T2 += pr[17+pp];
      }
      const float z   = rcpf(T0 + EPSF);
      const float mu  = T1 * z;
      const float s0  = T0 * z;
      const float var = fmaxf(T2*z - mu*mu*(2.f - s0), 0.f) + EPSF;
      sMu[cc*17 + pp]  = mu;
      sNI2[cc*17 + pp] = -0.5f * rcpf(var);
      float lsum = 0.5f * __logf(var);
      lsum += __shfl_xor(lsum, 1);  lsum += __shfl_xor(lsum, 2);
      lsum += __shfl_xor(lsum, 4);  lsum += __shfl_xor(lsum, 8);
      if (pp == 0) {
        const float cost = (16.f*beta_u[cc] + lsum) * T0;   // r_sum = T0
        const float ao = rcpf(1.f + __expf(-(LAMF*(beta_a[cc] - cost))));
        sAo[cc] = ao; sLnA[cc] = __logf(ao); sLs[cc] = lsum;
      }
    }
    __syncthreads();
  };

  // ---- sweep 0 (it=0): r uniform -> rr = f/32, accumulate moments ----
  t0 = 0.f;
#pragma unroll
  for (int p = 0; p < PS; ++p) { t1[p] = 0.f; t2[p] = 0.f; }
  for (int kt = 0; kt < KT; ++kt) {
    const int k = kt*16 + ks;
    const float4* wg = (const float4*)(wgt + (((size_t)(k*32 + c)) << 4));
    const float4 w0 = wg[0], w1 = wg[1], w2 = wg[2], w3 = wg[3];
    const int sw = (k>>1)&3;
    const float* pb = &sP[k<<4];
    const float4 Pi[4] = { ld4(pb + ((0^sw)<<2)), ld4(pb + ((1^sw)<<2)),
                           ld4(pb + ((2^sw)<<2)), ld4(pb + ((3^sw)<<2)) };
    const float rr = sA[k] * (1.0f/32.0f);
    t0 += rr;
#pragma unroll
    for (int i = 0; i < 4; ++i) {
      float v0 = Pi[i].x*w0.x; v0 = fmaf(Pi[i].y, w1.x, v0); v0 = fmaf(Pi[i].z, w2.x, v0); v0 = fmaf(Pi[i].w, w3.x, v0);
      float v1 = Pi[i].x*w0.y; v1 = fmaf(Pi[i].y, w1.y, v1); v1 = fmaf(Pi[i].z, w2.y, v1); v1 = fmaf(Pi[i].w, w3.y, v1);
      float v2 = Pi[i].x*w0.z; v2 = fmaf(Pi[i].y, w1.z, v2); v2 = fmaf(Pi[i].z, w2.z, v2); v2 = fmaf(Pi[i].w, w3.z, v2);
      float v3 = Pi[i].x*w0.w; v3 = fmaf(Pi[i].y, w1.w, v3); v3 = fmaf(Pi[i].z, w2.w, v3); v3 = fmaf(Pi[i].w, w3.w, v3);
      const float m0 = rr*v0, m1 = rr*v1, m2 = rr*v2, m3 = rr*v3;
      t1[i*4+0] += m0; t2[i*4+0] = fmaf(m0, v0, t2[i*4+0]);
      t1[i*4+1] += m1; t2[i*4+1] = fmaf(m1, v1, t2[i*4+1]);
      t1[i*4+2] += m2; t2[i*4+2] = fmaf(m2, v2, t2[i*4+2]);
      t1[i*4+3] += m3; t2[i*4+3] = fmaf(m3, v3, t2[i*4+3]);
    }
  }
  stats();

  // ---- sweeps 1,2: ln_p(prev mu,sigma) -> softmax -> rr -> moments ----
  for (int it = 1; it < 3; ++it) {
    float mu[PS], ni2[PS];
#pragma unroll
    for (int p = 0; p < PS; ++p) { mu[p] = sMu[c*17+p]; ni2[p] = sNI2[c*17+p]; }
    const float lc = sLnA[c] - sLs[c] - 16.f*HL2PI;
    t0 = 0.f;
#pragma unroll
    for (int p = 0; p < PS; ++p) { t1[p] = 0.f; t2[p] = 0.f; }
    for (int kt = 0; kt < KT; ++kt) {
      const int k = kt*16 + ks;
      const float4* wg = (const float4*)(wgt + (((size_t)(k*32 + c)) << 4));
      const float4 w0 = wg[0], w1 = wg[1], w2 = wg[2], w3 = wg[3];
      const int sw = (k>>1)&3;
      const float* pb = &sP[k<<4];
      const float4 Pi[4] = { ld4(pb + ((0^sw)<<2)), ld4(pb + ((1^sw)<<2)),
                             ld4(pb + ((2^sw)<<2)), ld4(pb + ((3^sw)<<2)) };
      float v[PS];
#pragma unroll
      for (int i = 0; i < 4; ++i) {
        float v0 = Pi[i].x*w0.x; v0 = fmaf(Pi[i].y, w1.x, v0); v0 = fmaf(Pi[i].z, w2.x, v0); v0 = fmaf(Pi[i].w, w3.x, v0);
        float v1 = Pi[i].x*w0.y; v1 = fmaf(Pi[i].y, w1.y, v1); v1 = fmaf(Pi[i].z, w2.y, v1); v1 = fmaf(Pi[i].w, w3.y, v1);
        float v2 = Pi[i].x*w0.z; v2 = fmaf(Pi[i].y, w1.z, v2); v2 = fmaf(Pi[i].z, w2.z, v2); v2 = fmaf(Pi[i].w, w3.z, v2);
        float v3 = Pi[i].x*w0.w; v3 = fmaf(Pi[i].y, w1.w, v3); v3 = fmaf(Pi[i].z, w2.w, v3); v3 = fmaf(Pi[i].w, w3.w, v3);
        v[i*4+0] = v0; v[i*4+1] = v1; v[i*4+2] = v2; v[i*4+3] = v3;
      }
      float acc = 0.f;
#pragma unroll
      for (int p = 0; p < PS; ++p) {
        const float d = v[p] - mu[p];
        acc = fmaf(d*d, ni2[p], acc);
      }
      const float lnap = acc + lc;
      float m = lnap;        // softmax over c within each 32-lane half
      m = fmaxf(m, __shfl_xor(m, 1));  m = fmaxf(m, __shfl_xor(m, 2));
      m = fmaxf(m, __shfl_xor(m, 4));  m = fmaxf(m, __shfl_xor(m, 8));
      m = fmaxf(m, __shfl_xor(m, 16));
      const float e = __expf(lnap - m);
      float s = e;
      s += __shfl_xor(s, 1);  s += __shfl_xor(s, 2);  s += __shfl_xor(s, 4);
      s += __shfl_xor(s, 8);  s += __shfl_xor(s, 16);
      const float rr = e * rcpf(s) * sA[k];    // r * a/(a+eps)
      t0 += rr;
#pragma unroll
      for (int p = 0; p < PS; ++p) {
        const float tmp = rr * v[p];
        t1[p] += tmp;
        t2[p] = fmaf(tmp, v[p], t2[p]);
      }
    }
    stats();
  }

  // ---- epilogue ----
  out[(size_t)n*544 + tid] = sMu[(tid>>4)*17 + (tid&15)];
  if (tid < CC) out[(size_t)n*544 + 512 + tid] = sAo[tid];
}

extern "C" void kernel_launch(void* const* d_in, const int* in_sizes, int n_in,
                              void* d_out, int out_size, void* d_ws, size_t ws_size,
                              hipStream_t stream) {
  (void)in_sizes; (void)n_in; (void)d_ws; (void)ws_size; (void)out_size;
  const float* x  = (const float*)d_in[0];
  const float* w  = (const float*)d_in[1];
  const float* ba = (const float*)d_in[2];
  const float* bu = (const float*)d_in[3];
  float* out = (float*)d_out;
  convcaps_em_kernel<<<dim3(392), dim3(NTH), 0, stream>>>(x, w, ba, bu, out);
}